// Round 20
// baseline (334.045 us; speedup 1.0000x reference)
//
#include <hip/hip_runtime.h>
#include <hip/hip_bf16.h>

typedef unsigned short u16;
typedef u16   u16x4 __attribute__((ext_vector_type(4)));
typedef u16   u16x8 __attribute__((ext_vector_type(8)));
typedef short s16x4 __attribute__((ext_vector_type(4)));
typedef short s16x8 __attribute__((ext_vector_type(8)));
typedef float f32x2  __attribute__((ext_vector_type(2)));
typedef float f32x16 __attribute__((ext_vector_type(16)));

constexpr int Bc   = 16;
constexpr int DIMc = 384;
constexpr int Rc   = 28;
constexpr int NHc  = 8;
constexpr int KDc  = 32;
constexpr int Dc   = 128;
constexpr int DHc  = 1024;   // NH*D
constexpr int Nc   = 784;    // R*R
constexpr int Mrows = NHc * Nc;  // 6272
constexpr int BPASS = 8;         // batches per attention pass (SSb reuse)
constexpr float SCALEf = 0.17677669529663687f;  // 32^-0.5
constexpr float EPSf   = 1e-5f;

__device__ inline float bf2f(u16 u) {
    union { float f; unsigned i; } c; c.i = ((unsigned)u) << 16; return c.f;
}
__device__ inline u16 f2bf(float f) {
    __hip_bfloat16 h = __float2bfloat16(f);
    union { __hip_bfloat16 h; u16 u; } c; c.h = h; return c.u;
}
__device__ inline f32x16 zero16() {
    f32x16 z;
    #pragma unroll
    for (int i = 0; i < 16; i++) z[i] = 0.f;
    return z;
}
__device__ inline s16x8 ldfrag(const u16* p) {
    s16x4 lo = *(const s16x4*)p;
    s16x4 hi = *(const s16x4*)(p + 4);
    return __builtin_shufflevector(lo, hi, 0, 1, 2, 3, 4, 5, 6, 7);
}
__device__ inline f32x16 mfma32(s16x8 a, s16x8 b, f32x16 c) {
    return __builtin_amdgcn_mfma_f32_32x32x16_bf16(a, b, c, 0, 0, 0);
}
// packed fp32 FMA with scalar broadcast of src1.lo / src1.hi via op_sel
__device__ inline f32x2 pkfma_lo(f32x2 a, f32x2 b, f32x2 c) {
    asm("v_pk_fma_f32 %0, %1, %2, %0 op_sel:[0,0,0] op_sel_hi:[1,0,1]"
        : "+v"(c) : "v"(a), "v"(b));
    return c;
}
__device__ inline f32x2 pkfma_hi(f32x2 a, f32x2 b, f32x2 c) {
    asm("v_pk_fma_f32 %0, %1, %2, %0 op_sel:[0,1,0] op_sel_hi:[1,1,1]"
        : "+v"(c) : "v"(a), "v"(b));
    return c;
}

// ---------------------------------------------------------------------------
// tab2T[j][o] = sum_i th1w[o,i]*btab[i][j] + th1b[o]   (784 x 8 fp32, 25 KB)
// ---------------------------------------------------------------------------
__global__ __launch_bounds__(256) void tab2_kernel(
    const float* __restrict__ btab, const float* __restrict__ w1,
    const float* __restrict__ b1, float* __restrict__ tab2T)
{
    __shared__ float w1s[64], b1s[8];
    const int t = threadIdx.x;
    if (t < 64) w1s[t] = w1[t];
    if (t < 8)  b1s[t] = b1[t];
    __syncthreads();
    int e = blockIdx.x * 256 + t;          // e = j*8 + o
    if (e >= Nc * NHc) return;
    int j = e >> 3, o = e & 7;
    float s = b1s[o];
    #pragma unroll
    for (int i = 0; i < 8; i++) s += w1s[o * 8 + i] * btab[i * Nc + j];
    tab2T[e] = s;
}

// ---------------------------------------------------------------------------
// Fold BN (and extra scale) into bf16 weights + fp32 bias.
// ---------------------------------------------------------------------------
__global__ __launch_bounds__(256) void fold_w_kernel(
    const float* __restrict__ W, const float* __restrict__ b,
    const float* __restrict__ g, const float* __restrict__ bet,
    const float* __restrict__ m, const float* __restrict__ rv,
    float sc, u16* __restrict__ Wb, float* __restrict__ bb, int O, int K)
{
    int i = blockIdx.x * 256 + threadIdx.x;
    if (i >= O * K) return;
    int o = i / K;
    float inv = g[o] / sqrtf(rv[o] + EPSf);
    Wb[i] = f2bf(W[i] * inv * sc);
    if (i - o * K == 0) bb[o] = ((b[o] - m[o]) * inv + bet[o]) * sc;
}

// ---------------------------------------------------------------------------
// Cast + transpose x: xT[b][n][c] bf16 from x[b][c][n] fp32. 64x64 LDS tiles.
// ---------------------------------------------------------------------------
__global__ __launch_bounds__(256) void castx_kernel(
    const float* __restrict__ x, u16* __restrict__ xT)
{
    __shared__ float tile[64][65];
    const int t = threadIdx.x;
    const int n0 = blockIdx.x * 64;
    const int c0 = blockIdx.y * 64;
    const int b  = blockIdx.z;
    const int jj = (t & 15) * 4, ii = t >> 4;
    #pragma unroll
    for (int rep = 0; rep < 4; rep++) {
        int c = c0 + ii + rep * 16;
        if (n0 + jj < Nc) {
            float4 v = *reinterpret_cast<const float4*>(
                &x[((size_t)b * DIMc + c) * Nc + n0 + jj]);
            tile[ii + rep * 16][jj + 0] = v.x;
            tile[ii + rep * 16][jj + 1] = v.y;
            tile[ii + rep * 16][jj + 2] = v.z;
            tile[ii + rep * 16][jj + 3] = v.w;
        }
    }
    __syncthreads();
    const int cc = (t & 15) * 4;
    #pragma unroll
    for (int rep = 0; rep < 4; rep++) {
        int nn = (t >> 4) + rep * 16;
        int n  = n0 + nn;
        if (n < Nc) {
            u16x4 r;
            #pragma unroll
            for (int q = 0; q < 4; q++) r[q] = f2bf(tile[cc + q][nn]);
            *reinterpret_cast<u16x4*>(&xT[((size_t)b * Nc + n) * DIMc + c0 + cc]) = r;
        }
    }
}

// ---------------------------------------------------------------------------
// Unified bf16 MFMA GEMM: C[row][col] = sum_k A[row][k]*B[col][k] + bias.
// 128 x COLT tile, 4 waves, BK=64. xdiv>0 pins (col-panel,z) to one XCD.
// ---------------------------------------------------------------------------
template<int KK, int COLT, bool XYSWAP, bool BGUARD, bool BIAS_COL, bool OUTF32>
__global__ __launch_bounds__(256) void mfma_gemm(
    const u16* __restrict__ A, const u16* __restrict__ B,
    const float* __restrict__ bias, u16* __restrict__ Cb,
    float* __restrict__ Cf, size_t zB, size_t zC, int zBias,
    int xdiv, int ldC, int Bvalid)
{
    constexpr int NI = COLT / 64;            // 2 or 1
    __shared__ u16 Asb[128][68];
    __shared__ u16 Bsb[COLT][68];
    const int t = threadIdx.x;
    int bx, by, zz;
    if (xdiv > 0) {
        bx = blockIdx.x % xdiv;
        zz = blockIdx.x / xdiv;
        by = blockIdx.y;
    } else {
        bx = XYSWAP ? blockIdx.y : blockIdx.x;
        by = XYSWAP ? blockIdx.x : blockIdx.y;
        zz = blockIdx.z;
    }
    const int col0 = bx * COLT;
    const int A0   = by * 128;
    const u16* Bz  = B + zB * (size_t)zz;
    const float* bz = bias + (size_t)zBias * zz;
    const int w = t >> 6, l = t & 63;
    const int lrow = l & 31, lhalf = l >> 5;
    const int rsub = w & 1, csub = w >> 1;

    f32x16 acc[2][NI];
    #pragma unroll
    for (int di = 0; di < 2; di++)
        #pragma unroll
        for (int ni = 0; ni < NI; ni++) acc[di][ni] = zero16();

    for (int kc = 0; kc < KK; kc += 64) {
        #pragma unroll
        for (int cc = 0; cc < 4; cc++) {          // A: 128 rows x 64 k
            int ch  = t + 256 * cc;
            int row = ch >> 3;
            int c8  = (ch & 7) * 8;
            u16x8 va = *reinterpret_cast<const u16x8*>(
                &A[(size_t)(A0 + row) * KK + kc + c8]);
            *reinterpret_cast<u16x4*>(&Asb[row][c8])     = (u16x4){va[0],va[1],va[2],va[3]};
            *reinterpret_cast<u16x4*>(&Asb[row][c8 + 4]) = (u16x4){va[4],va[5],va[6],va[7]};
        }
        #pragma unroll
        for (int cc = 0; cc < COLT / 32; cc++) {  // B: COLT rows x 64 k
            int ch  = t + 256 * cc;
            int row = ch >> 3;
            int c8  = (ch & 7) * 8;
            u16x8 vb;
            if (!BGUARD || col0 + row < Bvalid)
                vb = *reinterpret_cast<const u16x8*>(
                    &Bz[(size_t)(col0 + row) * KK + kc + c8]);
            else
                #pragma unroll
                for (int q = 0; q < 8; q++) vb[q] = 0;
            *reinterpret_cast<u16x4*>(&Bsb[row][c8])     = (u16x4){vb[0],vb[1],vb[2],vb[3]};
            *reinterpret_cast<u16x4*>(&Bsb[row][c8 + 4]) = (u16x4){vb[4],vb[5],vb[6],vb[7]};
        }
        __syncthreads();
        #pragma unroll
        for (int k0 = 0; k0 < 64; k0 += 16) {
            s16x8 af[2], bf[NI];
            #pragma unroll
            for (int di = 0; di < 2; di++)
                af[di] = ldfrag(&Asb[rsub * 64 + di * 32 + lrow][k0 + lhalf * 8]);
            #pragma unroll
            for (int ni = 0; ni < NI; ni++)
                bf[ni] = ldfrag(&Bsb[csub * (COLT / 2) + ni * 32 + lrow][k0 + lhalf * 8]);
            #pragma unroll
            for (int di = 0; di < 2; di++)
                #pragma unroll
                for (int ni = 0; ni < NI; ni++)
                    acc[di][ni] = mfma32(af[di], bf[ni], acc[di][ni]);
        }
        __syncthreads();
    }

    #pragma unroll
    for (int di = 0; di < 2; di++) {
        #pragma unroll
        for (int ni = 0; ni < NI; ni++) {
            int col = col0 + csub * (COLT / 2) + ni * 32 + lrow;
            if (BGUARD && col >= Bvalid) continue;
            float bcol = BIAS_COL ? bz[col] : 0.f;
            #pragma unroll
            for (int reg = 0; reg < 16; reg++) {
                int row = A0 + rsub * 64 + di * 32 + (reg & 3) + 8 * (reg >> 2) + 4 * lhalf;
                float val = acc[di][ni][reg] + (BIAS_COL ? bcol : bz[row]);
                size_t off = zC * (size_t)zz + (size_t)row * ldC + col;
                if constexpr (OUTF32) Cf[off] = val;
                else                  Cb[off] = f2bf(val);
            }
        }
    }
}

// ---------------------------------------------------------------------------
// Depthwise 3x3 + BN, natural layout, bf16 in/out. One block per (b,c).
// ---------------------------------------------------------------------------
__global__ __launch_bounds__(256) void dwconv_bn_kernel(
    const u16* __restrict__ vnat, const float* __restrict__ wl,
    const float* __restrict__ bl, const float* __restrict__ gg,
    const float* __restrict__ bet, const float* __restrict__ mea,
    const float* __restrict__ rvv, u16* __restrict__ vloc)
{
    __shared__ float img[30][30];
    const int t = threadIdx.x;
    const int b = blockIdx.x >> 10;
    const int c = blockIdx.x & 1023;
    const u16* src = vnat + ((size_t)b * DHc + c) * Nc;

    for (int i = t; i < 900; i += 256) img[i / 30][i % 30] = 0.f;
    __syncthreads();
    if (t < 196) {
        u16x4 u = *reinterpret_cast<const u16x4*>(&src[t * 4]);
        int y = (t * 4) / 28, x = (t * 4) % 28;
        img[y + 1][x + 1] = bf2f(u[0]);
        img[y + 1][x + 2] = bf2f(u[1]);
        img[y + 1][x + 3] = bf2f(u[2]);
        img[y + 1][x + 4] = bf2f(u[3]);
    }
    __syncthreads();

    float wreg[9];
    #pragma unroll
    for (int i = 0; i < 9; i++) wreg[i] = wl[c * 9 + i];
    float inv = gg[c] / sqrtf(rvv[c] + EPSf);
    float sh  = bet[c] - mea[c] * inv + bl[c] * inv;

    for (int i = t; i < Nc; i += 256) {
        int y = i / 28, x = i % 28;
        float a = 0.f;
        #pragma unroll
        for (int dy = 0; dy < 3; dy++)
            #pragma unroll
            for (int dx = 0; dx < 3; dx++)
                a += img[y + dy][x + dx] * wreg[dy * 3 + dx];
        vloc[((size_t)b * DHc + c) * Nc + i] = f2bf(a * inv + sh);
    }
}

// ---------------------------------------------------------------------------
// Per-head raw scores. SSb layout: [lb][n][head][m] bf16.
// ---------------------------------------------------------------------------
__global__ __launch_bounds__(256) void qk_kernel(
    const u16* __restrict__ qsb, const u16* __restrict__ Kt,
    u16* __restrict__ SSb, int b0)
{
    __shared__ u16 Asb[128][36];
    __shared__ u16 Bsb[128][36];
    const int t  = threadIdx.x;
    const int m0 = blockIdx.x * 128;
    const int n0 = blockIdx.y * 128;
    const int z  = blockIdx.z;
    const int lb = z >> 3, hi = z & 7;
    const int gb = b0 + lb;
    const int w = t >> 6, l = t & 63;
    const int lrow = l & 31, lhalf = l >> 5;
    const int nsub = w & 1, msub = w >> 1;

    #pragma unroll
    for (int cc = 0; cc < 2; cc++) {
        int ch  = t + 256 * cc;
        int row = ch >> 2;
        int c8  = (ch & 3) * 8;
        u16x8 va, vb;
        if (n0 + row < Nc)
            va = *reinterpret_cast<const u16x8*>(
                &qsb[((size_t)gb * Nc + n0 + row) * 256 + hi * 32 + c8]);
        else
            #pragma unroll
            for (int q = 0; q < 8; q++) va[q] = 0;
        if (m0 + row < Nc)
            vb = *reinterpret_cast<const u16x8*>(
                &Kt[((size_t)gb * Nc + m0 + row) * 256 + hi * 32 + c8]);
        else
            #pragma unroll
            for (int q = 0; q < 8; q++) vb[q] = 0;
        *reinterpret_cast<u16x4*>(&Asb[row][c8])     = (u16x4){va[0],va[1],va[2],va[3]};
        *reinterpret_cast<u16x4*>(&Asb[row][c8 + 4]) = (u16x4){va[4],va[5],va[6],va[7]};
        *reinterpret_cast<u16x4*>(&Bsb[row][c8])     = (u16x4){vb[0],vb[1],vb[2],vb[3]};
        *reinterpret_cast<u16x4*>(&Bsb[row][c8 + 4]) = (u16x4){vb[4],vb[5],vb[6],vb[7]};
    }
    __syncthreads();

    f32x16 acc[2][2];
    acc[0][0] = zero16(); acc[0][1] = zero16();
    acc[1][0] = zero16(); acc[1][1] = zero16();

    #pragma unroll
    for (int k0 = 0; k0 < 32; k0 += 16) {
        s16x8 af[2], bf[2];
        #pragma unroll
        for (int di = 0; di < 2; di++)
            af[di] = ldfrag(&Asb[nsub * 64 + di * 32 + lrow][k0 + lhalf * 8]);
        #pragma unroll
        for (int ni = 0; ni < 2; ni++)
            bf[ni] = ldfrag(&Bsb[msub * 64 + ni * 32 + lrow][k0 + lhalf * 8]);
        #pragma unroll
        for (int di = 0; di < 2; di++)
            #pragma unroll
            for (int ni = 0; ni < 2; ni++)
                acc[di][ni] = mfma32(af[di], bf[ni], acc[di][ni]);
    }

    #pragma unroll
    for (int di = 0; di < 2; di++) {
        #pragma unroll
        for (int ni = 0; ni < 2; ni++) {
            int mcol = m0 + msub * 64 + ni * 32 + lrow;
            if (mcol >= Nc) continue;
            #pragma unroll
            for (int reg = 0; reg < 16; reg++) {
                int nrow = n0 + nsub * 64 + di * 32 + (reg & 3) + 8 * (reg >> 2) + 4 * lhalf;
                if (nrow < Nc)
                    SSb[(((size_t)lb * Nc + nrow) * NHc + hi) * Nc + mcol] =
                        f2bf(acc[di][ni][reg]);
            }
        }
    }
}

// ---------------------------------------------------------------------------
// Fused TH1+bias + softmax + TH2 on SSb ([lb][n][head][m] layout, bf16).
// TH1/TH2 via v_pk_fma_f32 with op_sel broadcast (o-pairs per instruction).
// ---------------------------------------------------------------------------
__global__ __launch_bounds__(256) void smth2_kernel(
    u16* __restrict__ SSb, const float* __restrict__ th1w,
    const float* __restrict__ tab2T, const int* __restrict__ bidx,
    const float* __restrict__ w2, const float* __restrict__ b2)
{
    __shared__ f32x2 w1ps[8][4];   // [i][opair]
    __shared__ f32x2 w2ps[8][4];
    __shared__ float b2s[8];
    __shared__ float red[4][8];
    const int t = threadIdx.x;
    const int n = blockIdx.x;
    const int b = blockIdx.y;
    const int wv = t >> 6, l = t & 63;
    if (t < 32) {
        int i = t >> 2, op = t & 3;
        w1ps[i][op] = (f32x2){th1w[(2 * op) * 8 + i], th1w[(2 * op + 1) * 8 + i]};
        w2ps[i][op] = (f32x2){w2[(2 * op) * 8 + i],   w2[(2 * op + 1) * 8 + i]};
    }
    if (t < 8) b2s[t] = b2[t];
    __syncthreads();

    const size_t rowbase = ((size_t)(b * Nc + n) * NHc) * Nc;  // + o*Nc + m
    const bool act = (t < 196);
    const int m0 = t * 4;

    // ---- pass 1: load + TH1(pk) + bias + exp, per-thread row sums ----
    f32x2 mix2[4][4];          // [q][opair] over heads (2op, 2op+1)
    float lsum[8];
    #pragma unroll
    for (int o = 0; o < 8; o++) lsum[o] = 0.f;
    if (act) {
        int4 idx4 = *reinterpret_cast<const int4*>(&bidx[n * Nc + m0]);
        const int* idxp = &idx4.x;
        u16x4 su[8];
        #pragma unroll
        for (int i = 0; i < 8; i++)
            su[i] = *reinterpret_cast<const u16x4*>(
                &SSb[rowbase + (size_t)i * Nc + m0]);
        #pragma unroll
        for (int q = 0; q < 4; q++) {
            const float* tp = &tab2T[idxp[q] * 8];
            #pragma unroll
            for (int op = 0; op < 4; op++)
                mix2[q][op] = *reinterpret_cast<const f32x2*>(tp + 2 * op);
            f32x2 s2[4];
            #pragma unroll
            for (int j = 0; j < 4; j++)
                s2[j] = (f32x2){bf2f(su[2 * j][q]), bf2f(su[2 * j + 1][q])};
            #pragma unroll
            for (int j = 0; j < 4; j++) {
                #pragma unroll
                for (int op = 0; op < 4; op++)
                    mix2[q][op] = pkfma_lo(w1ps[2 * j][op], s2[j], mix2[q][op]);
                #pragma unroll
                for (int op = 0; op < 4; op++)
                    mix2[q][op] = pkfma_hi(w1ps[2 * j + 1][op], s2[j], mix2[q][op]);
            }
            #pragma unroll
            for (int op = 0; op < 4; op++) {
                float ex = __expf(mix2[q][op].x);
                float ey = __expf(mix2[q][op].y);
                mix2[q][op] = (f32x2){ex, ey};
                lsum[2 * op]     += ex;
                lsum[2 * op + 1] += ey;
            }
        }
    } else {
        #pragma unroll
        for (int q = 0; q < 4; q++)
            #pragma unroll
            for (int op = 0; op < 4; op++) mix2[q][op] = (f32x2){0.f, 0.f};
    }
    #pragma unroll
    for (int o = 0; o < 8; o++)
        #pragma unroll
        for (int off = 32; off; off >>= 1)
            lsum[o] += __shfl_xor(lsum[o], off);
    if (l == 0) {
        #pragma unroll
        for (int o = 0; o < 8; o++) red[wv][o] = lsum[o];
    }
    __syncthreads();

    // ---- pass 2: normalize (packed) + TH2(pk) + store bf16 ----
    if (act) {
        f32x2 iv2[4];
        #pragma unroll
        for (int op = 0; op < 4; op++) {
            float ia = 1.0f / (red[0][2*op]   + red[1][2*op]   + red[2][2*op]   + red[3][2*op]);
            float ib = 1.0f / (red[0][2*op+1] + red[1][2*op+1] + red[2][2*op+1] + red[3][2*op+1]);
            iv2[op] = (f32x2){ia, ib};
        }
        #pragma unroll
        for (int q = 0; q < 4; q++)
            #pragma unroll
            for (int op = 0; op < 4; op++)
                mix2[q][op] = (f32x2){mix2[q][op].x * iv2[op].x,
                                      mix2[q][op].y * iv2[op].y};
        #pragma unroll
        for (int op = 0; op < 4; op++) {
            u16x4 r0, r1;
            #pragma unroll
            for (int q = 0; q < 4; q++) {
                f32x2 o2 = (f32x2){b2s[2 * op], b2s[2 * op + 1]};
                #pragma unroll
                for (int j = 0; j < 4; j++) {
                    o2 = pkfma_lo(w2ps[2 * j][op],     mix2[q][j], o2);
                    o2 = pkfma_hi(w2ps[2 * j + 1][op], mix2[q][j], o2);
                }
                r0[q] = f2bf(o2.x);
                r1[q] = f2bf(o2.y);
            }
            *reinterpret_cast<u16x4*>(&SSb[rowbase + (size_t)(2 * op) * Nc + m0])     = r0;
            *reinterpret_cast<u16x4*>(&SSb[rowbase + (size_t)(2 * op + 1) * Nc + m0]) = r1;
        }
    }
}

// ---------------------------------------------------------------------------
// PV: attoT[gb][n][o*128+d] = sum_m P2[o,n,m] * v[o,m,d], bf16 out.
// 128-wide d tiles (P read exactly ONCE) + panel-XCD pinning:
//   blockIdx.x = panel + 64*tile, panel = o + 8*lb, gridDim.x = 448 (%8==0)
// ---------------------------------------------------------------------------
__global__ __launch_bounds__(256) void pv_kernel(
    const u16* __restrict__ SSb, const u16* __restrict__ vnat,
    u16* __restrict__ attoT, int b0)
{
    __shared__ u16 Vsb[128][36];   // [d][m]
    __shared__ u16 Psb[128][36];   // [n][m]
    const int t  = threadIdx.x;
    const int xx = blockIdx.x;
    const int panel = xx & 63;
    const int n0 = (xx >> 6) * 128;
    const int o  = panel & 7;
    const int lb = panel >> 3;
    const int gb = b0 + lb;
    const int w = t >> 6, l = t & 63;
    const int lrow = l & 31, lhalf = l >> 5;
    const int nsub = w & 1, dsub = w >> 1;

    f32x16 acc[2][2];
    acc[0][0] = zero16(); acc[0][1] = zero16();
    acc[1][0] = zero16(); acc[1][1] = zero16();

    for (int mc = 0; mc < 800; mc += 32) {
        #pragma unroll
        for (int cc = 0; cc < 2; cc++) {
            int ch  = t + 256 * cc;
            int row = ch >> 2;
            int c8  = (ch & 3) * 8;
            bool mok = (mc + c8 < Nc);
            u16x8 vv, pp;
            if (mok)
                vv = *reinterpret_cast<const u16x8*>(
                    &vnat[((size_t)gb * DHc + o * Dc + row) * Nc + mc + c8]);
            else
                #pragma unroll
                for (int q = 0; q < 8; q++) vv[q] = 0;
            if (mok && (n0 + row < Nc))
                pp = *reinterpret_cast<const u16x8*>(
                    &SSb[(((size_t)lb * Nc + n0 + row) * NHc + o) * Nc + mc + c8]);
            else
                #pragma unroll
                for (int q = 0; q < 8; q++) pp[q] = 0;
            *reinterpret_cast<u16x4*>(&Vsb[row][c8])     = (u16x4){vv[0],vv[1],vv[2],vv[3]};
            *reinterpret_cast<u16x4*>(&Vsb[row][c8 + 4]) = (u16x4){vv[4],vv[5],vv[6],vv[7]};
            *reinterpret_cast<u16x4*>(&Psb[row][c8])     = (u16x4){pp[0],pp[1],pp[2],pp[3]};
            *reinterpret_cast<u16x4*>(&Psb[row][c8 + 4]) = (u16x4){pp[4],pp[5],pp[6],pp[7]};
        }
        __syncthreads();
        #pragma unroll
        for (int k0 = 0; k0 < 32; k0 += 16) {
            s16x8 af[2], bf[2];
            #pragma unroll
            for (int di = 0; di < 2; di++)
                af[di] = ldfrag(&Psb[nsub * 64 + di * 32 + lrow][k0 + lhalf * 8]);
            #pragma unroll
            for (int ni = 0; ni < 2; ni++)
                bf[ni] = ldfrag(&Vsb[dsub * 64 + ni * 32 + lrow][k0 + lhalf * 8]);
            #pragma unroll
            for (int di = 0; di < 2; di++)
                #pragma unroll
                for (int ni = 0; ni < 2; ni++)
                    acc[di][ni] = mfma32(af[di], bf[ni], acc[di][ni]);
        }
        __syncthreads();
    }

    #pragma unroll
    for (int di = 0; di < 2; di++) {
        #pragma unroll
        for (int ni = 0; ni < 2; ni++) {
            int dcol = dsub * 64 + ni * 32 + lrow;
            #pragma unroll
            for (int reg = 0; reg < 16; reg++) {
                int nrow = n0 + nsub * 64 + di * 32 + (reg & 3) + 8 * (reg >> 2) + 4 * lhalf;
                if (nrow < Nc)
                    attoT[((size_t)gb * Nc + nrow) * DHc + o * Dc + dcol] =
                        f2bf(acc[di][ni][reg]);
            }
        }
    }
}

// ---------------------------------------------------------------------------
// pact[b][n][c] = bf16(relu(attoT[b][n][c] + vloc[b][c][n]^T)). 64x64 tiles.
// ---------------------------------------------------------------------------
__global__ __launch_bounds__(256) void prepP_kernel(
    const u16* __restrict__ attoT, const u16* __restrict__ vloc,
    u16* __restrict__ pact)
{
    __shared__ float tile[64][65];
    const int t = threadIdx.x;
    const int n0 = blockIdx.x * 64;
    const int c0 = blockIdx.y * 64;
    const int b  = blockIdx.z;
    const int jj = (t & 15) * 4, ii = t >> 4;
    #pragma unroll
    for (int rep = 0; rep < 4; rep++) {
        int c = c0 + ii + rep * 16;
        if (n0 + jj < Nc) {
            u16x4 v = *reinterpret_cast<const u16x4*>(
                &vloc[((size_t)b * DHc + c) * Nc + n0 + jj]);
            tile[ii + rep * 16][jj + 0] = bf2f(v[0]);
            tile[ii + rep * 16][jj + 1] = bf2f(v[1]);
            tile[ii + rep * 16][jj + 2] = bf2f(v[2]);
            tile[ii + rep * 16][jj + 3] = bf2f(v[3]);
        }
    }
    __syncthreads();
    const int cc = (t & 15) * 4;
    #pragma unroll
    for (int rep = 0; rep < 4; rep++) {
        int nn = (t >> 4) + rep * 16;
        int n  = n0 + nn;
        if (n < Nc) {
            size_t off = ((size_t)b * Nc + n) * DHc + c0 + cc;
            u16x4 a = *reinterpret_cast<const u16x4*>(&attoT[off]);
            u16x4 r;
            #pragma unroll
            for (int q = 0; q < 4; q++)
                r[q] = f2bf(fmaxf(bf2f(a[q]) + tile[cc + q][nn], 0.f));
            *reinterpret_cast<u16x4*>(&pact[off]) = r;
        }
    }
}

// ---------------------------------------------------------------------------
extern "C" void kernel_launch(void* const* d_in, const int* in_sizes, int n_in,
                              void* d_out, int out_size, void* d_ws, size_t ws_size,
                              hipStream_t stream)
{
    const float* x    = (const float*)d_in[0];
    const float* q_w  = (const float*)d_in[1];
    const float* q_b  = (const float*)d_in[2];
    const float* q_g  = (const float*)d_in[3];
    const float* q_be = (const float*)d_in[4];
    const float* q_m  = (const float*)d_in[5];
    const float* q_rv = (const float*)d_in[6];
    const float* k_w  = (const float*)d_in[7];
    const float* k_b  = (const float*)d_in[8];
    const float* k_g  = (const float*)d_in[9];
    const float* k_be = (const float*)d_in[10];
    const float* k_m  = (const float*)d_in[11];
    const float* k_rv = (const float*)d_in[12];
    const float* v_w  = (const float*)d_in[13];
    const float* v_b  = (const float*)d_in[14];
    const float* v_g  = (const float*)d_in[15];
    const float* v_be = (const float*)d_in[16];
    const float* v_m  = (const float*)d_in[17];
    const float* v_rv = (const float*)d_in[18];
    const float* vl_w = (const float*)d_in[19];
    const float* vl_b = (const float*)d_in[20];
    const float* vl_g = (const float*)d_in[21];
    const float* vl_be= (const float*)d_in[22];
    const float* vl_m = (const float*)d_in[23];
    const float* vl_rv= (const float*)d_in[24];
    const float* th1w = (const float*)d_in[25];
    const float* th1b = (const float*)d_in[26];
    const float* th2w = (const float*)d_in[27];
    const float* th2b = (const float*)d_in[28];
    const float* p_w  = (const float*)d_in[29];
    const float* p_b  = (const float*)d_in[30];
    const float* p_g  = (const float*)d_in[31];
    const float* p_be = (const float*)d_in[32];
    const float* p_m  = (const float*)d_in[33];
    const float* p_rv = (const float*)d_in[34];
    const float* btab = (const float*)d_in[35];
    const int*   bidx = (const int*)d_in[36];

    // ws ~170.6 MB (< 179.8 proven). Aliases:
    //  - xT: first 9.63 MB of attoT region (xT dead after projections).
    //  - pact aliases SSb (dead after last pv pass).
    char* wsb = (char*)d_ws;
    float* tab2T = (float*)wsb;                  wsb += (size_t)NHc * Nc * 4;
    u16*   qsb   = (u16*)wsb;                    wsb += (size_t)Bc * Nc * 256 * 2;
    u16*   Kt    = (u16*)wsb;                    wsb += (size_t)Bc * Nc * 256 * 2;
    u16*   vnat  = (u16*)wsb;                    wsb += (size_t)Bc * DHc * Nc * 2;
    u16*   vloc  = (u16*)wsb;                    wsb += (size_t)Bc * DHc * Nc * 2;
    u16*   SSb   = (u16*)wsb;                    wsb += (size_t)BPASS * Mrows * Nc * 2;
    u16*   qwb   = (u16*)wsb;                    wsb += (size_t)256 * DIMc * 2;
    u16*   kwb   = (u16*)wsb;                    wsb += (size_t)256 * DIMc * 2;
    u16*   vwb   = (u16*)wsb;                    wsb += (size_t)DHc * DIMc * 2;
    u16*   pwb   = (u16*)wsb;                    wsb += (size_t)DIMc * DHc * 2;
    float* qbb   = (float*)wsb;                  wsb += 256 * 4;
    float* kbb   = (float*)wsb;                  wsb += 256 * 4;
    float* vbb   = (float*)wsb;                  wsb += DHc * 4;
    float* pbb   = (float*)wsb;                  wsb += DIMc * 4;
    u16*   attoT = (u16*)wsb;                    wsb += (size_t)Bc * DHc * Nc * 2;
    u16*   xT    = attoT;   // alias: first 9.63 MB of attoT region
    u16*   pact  = SSb;     // alias: SSb dead after last pv pass

    tab2_kernel<<<dim3((Nc * NHc + 255) / 256), 256, 0, stream>>>(
        btab, th1w, th1b, tab2T);
    castx_kernel<<<dim3(13, 6, Bc), 256, 0, stream>>>(x, xT);
    fold_w_kernel<<<dim3((256 * DIMc + 255) / 256), 256, 0, stream>>>(
        q_w, q_b, q_g, q_be, q_m, q_rv, SCALEf, qwb, qbb, 256, DIMc);
    fold_w_kernel<<<dim3((256 * DIMc + 255) / 256), 256, 0, stream>>>(
        k_w, k_b, k_g, k_be, k_m, k_rv, 1.0f, kwb, kbb, 256, DIMc);
    fold_w_kernel<<<dim3((DHc * DIMc + 255) / 256), 256, 0, stream>>>(
        v_w, v_b, v_g, v_be, v_m, v_rv, 1.0f, vwb, vbb, DHc, DIMc);
    fold_w_kernel<<<dim3((DIMc * DHc + 255) / 256), 256, 0, stream>>>(
        p_w, p_b, p_g, p_be, p_m, p_rv, 1.0f, pwb, pbb, DIMc, DHc);

    // q+k proj fused (z=0 -> q, z=1 -> k): 392 blocks in one dispatch
    mfma_gemm<DIMc, 128, false, false, true, false><<<dim3(2, 98, 2), 256, 0, stream>>>(
        xT, qwb, qbb, qsb, nullptr,
        (size_t)256 * DIMc, (size_t)Bc * Nc * 256, 256, 0, 256, 256);
    // v proj: XCD-pinned panels (x = ntile + 7*z, gridDim.x = 112)
    mfma_gemm<DIMc, 128, false, true, false, false><<<dim3(112, 8, 1), 256, 0, stream>>>(
        vwb, xT, vbb, vnat, nullptr,
        (size_t)Nc * DIMc, (size_t)DHc * Nc, 0, 7, Nc, Nc);

    dwconv_bn_kernel<<<dim3(Bc * DHc), 256, 0, stream>>>(
        vnat, vl_w, vl_b, vl_g, vl_be, vl_m, vl_rv, vloc);

    for (int b0 = 0; b0 < Bc; b0 += BPASS) {
        qk_kernel<<<dim3(7, 7, BPASS * NHc), 256, 0, stream>>>(
            qsb, Kt, SSb, b0);
        smth2_kernel<<<dim3(Nc, BPASS), 256, 0, stream>>>(
            SSb, th1w, tab2T, bidx, th2w, th2b);
        pv_kernel<<<dim3(7 * 8 * BPASS), 256, 0, stream>>>(SSb, vnat, attoT, b0);
    }

    prepP_kernel<<<dim3(13, 16, Bc), 256, 0, stream>>>(attoT, vloc, pact);
    // p proj: 64-col tiles -> 624 blocks, fp32 out
    mfma_gemm<DHc, 64, false, true, false, true><<<dim3(13, 3, Bc), 256, 0, stream>>>(
        pwb, pact, pbb, nullptr, (float*)d_out,
        (size_t)Nc * DHc, (size_t)DIMc * Nc, 0, 0, Nc, Nc);
}

// Round 21
// 320.387 us; speedup vs baseline: 1.0426x; 1.0426x over previous
//
#include <hip/hip_runtime.h>
#include <hip/hip_bf16.h>

typedef unsigned short u16;
typedef u16   u16x4 __attribute__((ext_vector_type(4)));
typedef u16   u16x8 __attribute__((ext_vector_type(8)));
typedef short s16x4 __attribute__((ext_vector_type(4)));
typedef short s16x8 __attribute__((ext_vector_type(8)));
typedef float f32x2  __attribute__((ext_vector_type(2)));
typedef float f32x16 __attribute__((ext_vector_type(16)));

constexpr int Bc   = 16;
constexpr int DIMc = 384;
constexpr int Rc   = 28;
constexpr int NHc  = 8;
constexpr int KDc  = 32;
constexpr int Dc   = 128;
constexpr int DHc  = 1024;   // NH*D
constexpr int Nc   = 784;    // R*R
constexpr int Mrows = NHc * Nc;  // 6272
constexpr int BPASS = 8;         // batches per attention pass (SSb reuse)
constexpr float SCALEf = 0.17677669529663687f;  // 32^-0.5
constexpr float EPSf   = 1e-5f;

__device__ inline float bf2f(u16 u) {
    union { float f; unsigned i; } c; c.i = ((unsigned)u) << 16; return c.f;
}
__device__ inline u16 f2bf(float f) {
    __hip_bfloat16 h = __float2bfloat16(f);
    union { __hip_bfloat16 h; u16 u; } c; c.h = h; return c.u;
}
__device__ inline f32x16 zero16() {
    f32x16 z;
    #pragma unroll
    for (int i = 0; i < 16; i++) z[i] = 0.f;
    return z;
}
__device__ inline s16x8 ldfrag(const u16* p) {
    s16x4 lo = *(const s16x4*)p;
    s16x4 hi = *(const s16x4*)(p + 4);
    return __builtin_shufflevector(lo, hi, 0, 1, 2, 3, 4, 5, 6, 7);
}
__device__ inline f32x16 mfma32(s16x8 a, s16x8 b, f32x16 c) {
    return __builtin_amdgcn_mfma_f32_32x32x16_bf16(a, b, c, 0, 0, 0);
}
// packed fp32 FMA with scalar broadcast of src1.lo / src1.hi via op_sel
__device__ inline f32x2 pkfma_lo(f32x2 a, f32x2 b, f32x2 c) {
    asm("v_pk_fma_f32 %0, %1, %2, %0 op_sel:[0,0,0] op_sel_hi:[1,0,1]"
        : "+v"(c) : "v"(a), "v"(b));
    return c;
}
__device__ inline f32x2 pkfma_hi(f32x2 a, f32x2 b, f32x2 c) {
    asm("v_pk_fma_f32 %0, %1, %2, %0 op_sel:[0,1,0] op_sel_hi:[1,1,1]"
        : "+v"(c) : "v"(a), "v"(b));
    return c;
}

// ---------------------------------------------------------------------------
// Merged preamble: tab2 + castx + fold(q,k,v,p) in ONE dispatch (all
// independent). Block ranges:
//   [0,25)          tab2: tab2T[j*8+o]
//   [25,1273)       castx: xT[b][n][c] from x
//   [1273,1657)     fold q (scale = SCALEf)
//   [1657,2041)     fold k
//   [2041,3577)     fold v
//   [3577,5113)     fold p
// ---------------------------------------------------------------------------
__device__ inline void fold_body(
    int i, const float* W, const float* b, const float* g, const float* bet,
    const float* m, const float* rv, float sc, u16* Wb, float* bb, int O, int K)
{
    if (i >= O * K) return;
    int o = i / K;
    float inv = g[o] / sqrtf(rv[o] + EPSf);
    Wb[i] = f2bf(W[i] * inv * sc);
    if (i - o * K == 0) bb[o] = ((b[o] - m[o]) * inv + bet[o]) * sc;
}

__global__ __launch_bounds__(256) void prep_kernel(
    const float* __restrict__ btab, const float* __restrict__ w1,
    const float* __restrict__ b1, float* __restrict__ tab2T,
    const float* __restrict__ x, u16* __restrict__ xT,
    const float* __restrict__ q_w, const float* __restrict__ q_b,
    const float* __restrict__ q_g, const float* __restrict__ q_be,
    const float* __restrict__ q_m, const float* __restrict__ q_rv,
    u16* __restrict__ qwb, float* __restrict__ qbb,
    const float* __restrict__ k_w, const float* __restrict__ k_b,
    const float* __restrict__ k_g, const float* __restrict__ k_be,
    const float* __restrict__ k_m, const float* __restrict__ k_rv,
    u16* __restrict__ kwb, float* __restrict__ kbb,
    const float* __restrict__ v_w, const float* __restrict__ v_b,
    const float* __restrict__ v_g, const float* __restrict__ v_be,
    const float* __restrict__ v_m, const float* __restrict__ v_rv,
    u16* __restrict__ vwb, float* __restrict__ vbb,
    const float* __restrict__ p_w, const float* __restrict__ p_b,
    const float* __restrict__ p_g, const float* __restrict__ p_be,
    const float* __restrict__ p_m, const float* __restrict__ p_rv,
    u16* __restrict__ pwb, float* __restrict__ pbb)
{
    __shared__ float tile[64][65];
    __shared__ float w1s[64], b1s[8];
    const int bid = blockIdx.x;
    const int t = threadIdx.x;

    if (bid < 25) {
        // ---- tab2 ----
        if (t < 64) w1s[t] = w1[t];
        if (t < 8)  b1s[t] = b1[t];
        __syncthreads();
        int e = bid * 256 + t;
        if (e < Nc * NHc) {
            int j = e >> 3, o = e & 7;
            float s = b1s[o];
            #pragma unroll
            for (int i = 0; i < 8; i++) s += w1s[o * 8 + i] * btab[i * Nc + j];
            tab2T[e] = s;
        }
    } else if (bid < 1273) {
        // ---- castx (13 x 6 x 16) ----
        int rid = bid - 25;
        int nt = rid % 13;
        int ct = (rid / 13) % 6;
        int b  = rid / 78;
        const int n0 = nt * 64;
        const int c0 = ct * 64;
        const int jj = (t & 15) * 4, ii = t >> 4;
        #pragma unroll
        for (int rep = 0; rep < 4; rep++) {
            int c = c0 + ii + rep * 16;
            if (n0 + jj < Nc) {
                float4 v = *reinterpret_cast<const float4*>(
                    &x[((size_t)b * DIMc + c) * Nc + n0 + jj]);
                tile[ii + rep * 16][jj + 0] = v.x;
                tile[ii + rep * 16][jj + 1] = v.y;
                tile[ii + rep * 16][jj + 2] = v.z;
                tile[ii + rep * 16][jj + 3] = v.w;
            }
        }
        __syncthreads();
        const int cc = (t & 15) * 4;
        #pragma unroll
        for (int rep = 0; rep < 4; rep++) {
            int nn = (t >> 4) + rep * 16;
            int n  = n0 + nn;
            if (n < Nc) {
                u16x4 r;
                #pragma unroll
                for (int q = 0; q < 4; q++) r[q] = f2bf(tile[cc + q][nn]);
                *reinterpret_cast<u16x4*>(
                    &xT[((size_t)b * Nc + n) * DIMc + c0 + cc]) = r;
            }
        }
    } else if (bid < 1657) {
        fold_body((bid - 1273) * 256 + t, q_w, q_b, q_g, q_be, q_m, q_rv,
                  SCALEf, qwb, qbb, 256, DIMc);
    } else if (bid < 2041) {
        fold_body((bid - 1657) * 256 + t, k_w, k_b, k_g, k_be, k_m, k_rv,
                  1.0f, kwb, kbb, 256, DIMc);
    } else if (bid < 3577) {
        fold_body((bid - 2041) * 256 + t, v_w, v_b, v_g, v_be, v_m, v_rv,
                  1.0f, vwb, vbb, DHc, DIMc);
    } else {
        fold_body((bid - 3577) * 256 + t, p_w, p_b, p_g, p_be, p_m, p_rv,
                  1.0f, pwb, pbb, DIMc, DHc);
    }
}

// ---------------------------------------------------------------------------
// Unified bf16 MFMA GEMM: C[row][col] = sum_k A[row][k]*B[col][k] + bias.
// 128 x COLT tile, 4 waves, BK=64. xdiv>0 pins (col-panel,z) to one XCD.
// ---------------------------------------------------------------------------
template<int KK, int COLT, bool XYSWAP, bool BGUARD, bool BIAS_COL, bool OUTF32>
__global__ __launch_bounds__(256) void mfma_gemm(
    const u16* __restrict__ A, const u16* __restrict__ B,
    const float* __restrict__ bias, u16* __restrict__ Cb,
    float* __restrict__ Cf, size_t zB, size_t zC, int zBias,
    int xdiv, int ldC, int Bvalid)
{
    constexpr int NI = COLT / 64;            // 2 or 1
    __shared__ u16 Asb[128][68];
    __shared__ u16 Bsb[COLT][68];
    const int t = threadIdx.x;
    int bx, by, zz;
    if (xdiv > 0) {
        bx = blockIdx.x % xdiv;
        zz = blockIdx.x / xdiv;
        by = blockIdx.y;
    } else {
        bx = XYSWAP ? blockIdx.y : blockIdx.x;
        by = XYSWAP ? blockIdx.x : blockIdx.y;
        zz = blockIdx.z;
    }
    const int col0 = bx * COLT;
    const int A0   = by * 128;
    const u16* Bz  = B + zB * (size_t)zz;
    const float* bz = bias + (size_t)zBias * zz;
    const int w = t >> 6, l = t & 63;
    const int lrow = l & 31, lhalf = l >> 5;
    const int rsub = w & 1, csub = w >> 1;

    f32x16 acc[2][NI];
    #pragma unroll
    for (int di = 0; di < 2; di++)
        #pragma unroll
        for (int ni = 0; ni < NI; ni++) acc[di][ni] = zero16();

    for (int kc = 0; kc < KK; kc += 64) {
        #pragma unroll
        for (int cc = 0; cc < 4; cc++) {          // A: 128 rows x 64 k
            int ch  = t + 256 * cc;
            int row = ch >> 3;
            int c8  = (ch & 7) * 8;
            u16x8 va = *reinterpret_cast<const u16x8*>(
                &A[(size_t)(A0 + row) * KK + kc + c8]);
            *reinterpret_cast<u16x4*>(&Asb[row][c8])     = (u16x4){va[0],va[1],va[2],va[3]};
            *reinterpret_cast<u16x4*>(&Asb[row][c8 + 4]) = (u16x4){va[4],va[5],va[6],va[7]};
        }
        #pragma unroll
        for (int cc = 0; cc < COLT / 32; cc++) {  // B: COLT rows x 64 k
            int ch  = t + 256 * cc;
            int row = ch >> 3;
            int c8  = (ch & 7) * 8;
            u16x8 vb;
            if (!BGUARD || col0 + row < Bvalid)
                vb = *reinterpret_cast<const u16x8*>(
                    &Bz[(size_t)(col0 + row) * KK + kc + c8]);
            else
                #pragma unroll
                for (int q = 0; q < 8; q++) vb[q] = 0;
            *reinterpret_cast<u16x4*>(&Bsb[row][c8])     = (u16x4){vb[0],vb[1],vb[2],vb[3]};
            *reinterpret_cast<u16x4*>(&Bsb[row][c8 + 4]) = (u16x4){vb[4],vb[5],vb[6],vb[7]};
        }
        __syncthreads();
        #pragma unroll
        for (int k0 = 0; k0 < 64; k0 += 16) {
            s16x8 af[2], bf[NI];
            #pragma unroll
            for (int di = 0; di < 2; di++)
                af[di] = ldfrag(&Asb[rsub * 64 + di * 32 + lrow][k0 + lhalf * 8]);
            #pragma unroll
            for (int ni = 0; ni < NI; ni++)
                bf[ni] = ldfrag(&Bsb[csub * (COLT / 2) + ni * 32 + lrow][k0 + lhalf * 8]);
            #pragma unroll
            for (int di = 0; di < 2; di++)
                #pragma unroll
                for (int ni = 0; ni < NI; ni++)
                    acc[di][ni] = mfma32(af[di], bf[ni], acc[di][ni]);
        }
        __syncthreads();
    }

    #pragma unroll
    for (int di = 0; di < 2; di++) {
        #pragma unroll
        for (int ni = 0; ni < NI; ni++) {
            int col = col0 + csub * (COLT / 2) + ni * 32 + lrow;
            if (BGUARD && col >= Bvalid) continue;
            float bcol = BIAS_COL ? bz[col] : 0.f;
            #pragma unroll
            for (int reg = 0; reg < 16; reg++) {
                int row = A0 + rsub * 64 + di * 32 + (reg & 3) + 8 * (reg >> 2) + 4 * lhalf;
                float val = acc[di][ni][reg] + (BIAS_COL ? bcol : bz[row]);
                size_t off = zC * (size_t)zz + (size_t)row * ldC + col;
                if constexpr (OUTF32) Cf[off] = val;
                else                  Cb[off] = f2bf(val);
            }
        }
    }
}

// ---------------------------------------------------------------------------
// Depthwise 3x3 + BN, natural layout, bf16 in/out. One block per (b,c).
// ---------------------------------------------------------------------------
__global__ __launch_bounds__(256) void dwconv_bn_kernel(
    const u16* __restrict__ vnat, const float* __restrict__ wl,
    const float* __restrict__ bl, const float* __restrict__ gg,
    const float* __restrict__ bet, const float* __restrict__ mea,
    const float* __restrict__ rvv, u16* __restrict__ vloc)
{
    __shared__ float img[30][30];
    const int t = threadIdx.x;
    const int b = blockIdx.x >> 10;
    const int c = blockIdx.x & 1023;
    const u16* src = vnat + ((size_t)b * DHc + c) * Nc;

    for (int i = t; i < 900; i += 256) img[i / 30][i % 30] = 0.f;
    __syncthreads();
    if (t < 196) {
        u16x4 u = *reinterpret_cast<const u16x4*>(&src[t * 4]);
        int y = (t * 4) / 28, x = (t * 4) % 28;
        img[y + 1][x + 1] = bf2f(u[0]);
        img[y + 1][x + 2] = bf2f(u[1]);
        img[y + 1][x + 3] = bf2f(u[2]);
        img[y + 1][x + 4] = bf2f(u[3]);
    }
    __syncthreads();

    float wreg[9];
    #pragma unroll
    for (int i = 0; i < 9; i++) wreg[i] = wl[c * 9 + i];
    float inv = gg[c] / sqrtf(rvv[c] + EPSf);
    float sh  = bet[c] - mea[c] * inv + bl[c] * inv;

    for (int i = t; i < Nc; i += 256) {
        int y = i / 28, x = i % 28;
        float a = 0.f;
        #pragma unroll
        for (int dy = 0; dy < 3; dy++)
            #pragma unroll
            for (int dx = 0; dx < 3; dx++)
                a += img[y + dy][x + dx] * wreg[dy * 3 + dx];
        vloc[((size_t)b * DHc + c) * Nc + i] = f2bf(a * inv + sh);
    }
}

// ---------------------------------------------------------------------------
// Per-head raw scores. SSb layout: [lb][n][head][m] bf16.
// ---------------------------------------------------------------------------
__global__ __launch_bounds__(256) void qk_kernel(
    const u16* __restrict__ qsb, const u16* __restrict__ Kt,
    u16* __restrict__ SSb, int b0)
{
    __shared__ u16 Asb[128][36];
    __shared__ u16 Bsb[128][36];
    const int t  = threadIdx.x;
    const int m0 = blockIdx.x * 128;
    const int n0 = blockIdx.y * 128;
    const int z  = blockIdx.z;
    const int lb = z >> 3, hi = z & 7;
    const int gb = b0 + lb;
    const int w = t >> 6, l = t & 63;
    const int lrow = l & 31, lhalf = l >> 5;
    const int nsub = w & 1, msub = w >> 1;

    #pragma unroll
    for (int cc = 0; cc < 2; cc++) {
        int ch  = t + 256 * cc;
        int row = ch >> 2;
        int c8  = (ch & 3) * 8;
        u16x8 va, vb;
        if (n0 + row < Nc)
            va = *reinterpret_cast<const u16x8*>(
                &qsb[((size_t)gb * Nc + n0 + row) * 256 + hi * 32 + c8]);
        else
            #pragma unroll
            for (int q = 0; q < 8; q++) va[q] = 0;
        if (m0 + row < Nc)
            vb = *reinterpret_cast<const u16x8*>(
                &Kt[((size_t)gb * Nc + m0 + row) * 256 + hi * 32 + c8]);
        else
            #pragma unroll
            for (int q = 0; q < 8; q++) vb[q] = 0;
        *reinterpret_cast<u16x4*>(&Asb[row][c8])     = (u16x4){va[0],va[1],va[2],va[3]};
        *reinterpret_cast<u16x4*>(&Asb[row][c8 + 4]) = (u16x4){va[4],va[5],va[6],va[7]};
        *reinterpret_cast<u16x4*>(&Bsb[row][c8])     = (u16x4){vb[0],vb[1],vb[2],vb[3]};
        *reinterpret_cast<u16x4*>(&Bsb[row][c8 + 4]) = (u16x4){vb[4],vb[5],vb[6],vb[7]};
    }
    __syncthreads();

    f32x16 acc[2][2];
    acc[0][0] = zero16(); acc[0][1] = zero16();
    acc[1][0] = zero16(); acc[1][1] = zero16();

    #pragma unroll
    for (int k0 = 0; k0 < 32; k0 += 16) {
        s16x8 af[2], bf[2];
        #pragma unroll
        for (int di = 0; di < 2; di++)
            af[di] = ldfrag(&Asb[nsub * 64 + di * 32 + lrow][k0 + lhalf * 8]);
        #pragma unroll
        for (int ni = 0; ni < 2; ni++)
            bf[ni] = ldfrag(&Bsb[msub * 64 + ni * 32 + lrow][k0 + lhalf * 8]);
        #pragma unroll
        for (int di = 0; di < 2; di++)
            #pragma unroll
            for (int ni = 0; ni < 2; ni++)
                acc[di][ni] = mfma32(af[di], bf[ni], acc[di][ni]);
    }

    #pragma unroll
    for (int di = 0; di < 2; di++) {
        #pragma unroll
        for (int ni = 0; ni < 2; ni++) {
            int mcol = m0 + msub * 64 + ni * 32 + lrow;
            if (mcol >= Nc) continue;
            #pragma unroll
            for (int reg = 0; reg < 16; reg++) {
                int nrow = n0 + nsub * 64 + di * 32 + (reg & 3) + 8 * (reg >> 2) + 4 * lhalf;
                if (nrow < Nc)
                    SSb[(((size_t)lb * Nc + nrow) * NHc + hi) * Nc + mcol] =
                        f2bf(acc[di][ni][reg]);
            }
        }
    }
}

// ---------------------------------------------------------------------------
// Fused TH1+bias + softmax + TH2 on SSb ([lb][n][head][m] layout, bf16).
// REVERSED traversal (n = 783-x, lb = 7-y) so the first blocks read the S
// panels most recently written by qk (still L2-resident) -> higher hit rate.
// ---------------------------------------------------------------------------
__global__ __launch_bounds__(256) void smth2_kernel(
    u16* __restrict__ SSb, const float* __restrict__ th1w,
    const float* __restrict__ tab2T, const int* __restrict__ bidx,
    const float* __restrict__ w2, const float* __restrict__ b2)
{
    __shared__ f32x2 w1ps[8][4];   // [i][opair]
    __shared__ f32x2 w2ps[8][4];
    __shared__ float b2s[8];
    __shared__ float red[4][8];
    const int t = threadIdx.x;
    const int n = (Nc - 1) - blockIdx.x;
    const int b = (BPASS - 1) - blockIdx.y;
    const int wv = t >> 6, l = t & 63;
    if (t < 32) {
        int i = t >> 2, op = t & 3;
        w1ps[i][op] = (f32x2){th1w[(2 * op) * 8 + i], th1w[(2 * op + 1) * 8 + i]};
        w2ps[i][op] = (f32x2){w2[(2 * op) * 8 + i],   w2[(2 * op + 1) * 8 + i]};
    }
    if (t < 8) b2s[t] = b2[t];
    __syncthreads();

    const size_t rowbase = ((size_t)(b * Nc + n) * NHc) * Nc;  // + o*Nc + m
    const bool act = (t < 196);
    const int m0 = t * 4;

    // ---- pass 1: load + TH1(pk) + bias + exp, per-thread row sums ----
    f32x2 mix2[4][4];          // [q][opair] over heads (2op, 2op+1)
    float lsum[8];
    #pragma unroll
    for (int o = 0; o < 8; o++) lsum[o] = 0.f;
    if (act) {
        int4 idx4 = *reinterpret_cast<const int4*>(&bidx[n * Nc + m0]);
        const int* idxp = &idx4.x;
        u16x4 su[8];
        #pragma unroll
        for (int i = 0; i < 8; i++)
            su[i] = *reinterpret_cast<const u16x4*>(
                &SSb[rowbase + (size_t)i * Nc + m0]);
        #pragma unroll
        for (int q = 0; q < 4; q++) {
            const float* tp = &tab2T[idxp[q] * 8];
            #pragma unroll
            for (int op = 0; op < 4; op++)
                mix2[q][op] = *reinterpret_cast<const f32x2*>(tp + 2 * op);
            f32x2 s2[4];
            #pragma unroll
            for (int j = 0; j < 4; j++)
                s2[j] = (f32x2){bf2f(su[2 * j][q]), bf2f(su[2 * j + 1][q])};
            #pragma unroll
            for (int j = 0; j < 4; j++) {
                #pragma unroll
                for (int op = 0; op < 4; op++)
                    mix2[q][op] = pkfma_lo(w1ps[2 * j][op], s2[j], mix2[q][op]);
                #pragma unroll
                for (int op = 0; op < 4; op++)
                    mix2[q][op] = pkfma_hi(w1ps[2 * j + 1][op], s2[j], mix2[q][op]);
            }
            #pragma unroll
            for (int op = 0; op < 4; op++) {
                float ex = __expf(mix2[q][op].x);
                float ey = __expf(mix2[q][op].y);
                mix2[q][op] = (f32x2){ex, ey};
                lsum[2 * op]     += ex;
                lsum[2 * op + 1] += ey;
            }
        }
    } else {
        #pragma unroll
        for (int q = 0; q < 4; q++)
            #pragma unroll
            for (int op = 0; op < 4; op++) mix2[q][op] = (f32x2){0.f, 0.f};
    }
    #pragma unroll
    for (int o = 0; o < 8; o++)
        #pragma unroll
        for (int off = 32; off; off >>= 1)
            lsum[o] += __shfl_xor(lsum[o], off);
    if (l == 0) {
        #pragma unroll
        for (int o = 0; o < 8; o++) red[wv][o] = lsum[o];
    }
    __syncthreads();

    // ---- pass 2: normalize (packed) + TH2(pk) + store bf16 ----
    if (act) {
        f32x2 iv2[4];
        #pragma unroll
        for (int op = 0; op < 4; op++) {
            float ia = 1.0f / (red[0][2*op]   + red[1][2*op]   + red[2][2*op]   + red[3][2*op]);
            float ib = 1.0f / (red[0][2*op+1] + red[1][2*op+1] + red[2][2*op+1] + red[3][2*op+1]);
            iv2[op] = (f32x2){ia, ib};
        }
        #pragma unroll
        for (int q = 0; q < 4; q++)
            #pragma unroll
            for (int op = 0; op < 4; op++)
                mix2[q][op] = (f32x2){mix2[q][op].x * iv2[op].x,
                                      mix2[q][op].y * iv2[op].y};
        #pragma unroll
        for (int op = 0; op < 4; op++) {
            u16x4 r0, r1;
            #pragma unroll
            for (int q = 0; q < 4; q++) {
                f32x2 o2 = (f32x2){b2s[2 * op], b2s[2 * op + 1]};
                #pragma unroll
                for (int j = 0; j < 4; j++) {
                    o2 = pkfma_lo(w2ps[2 * j][op],     mix2[q][j], o2);
                    o2 = pkfma_hi(w2ps[2 * j + 1][op], mix2[q][j], o2);
                }
                r0[q] = f2bf(o2.x);
                r1[q] = f2bf(o2.y);
            }
            *reinterpret_cast<u16x4*>(&SSb[rowbase + (size_t)(2 * op) * Nc + m0])     = r0;
            *reinterpret_cast<u16x4*>(&SSb[rowbase + (size_t)(2 * op + 1) * Nc + m0]) = r1;
        }
    }
}

// ---------------------------------------------------------------------------
// PV: attoT[gb][n][o*128+d] = sum_m P2[o,n,m] * v[o,m,d], bf16 out.
// 128-wide d tiles (P read exactly ONCE) + panel-XCD pinning:
//   blockIdx.x = panel + 64*tile, panel = o + 8*lb, gridDim.x = 448 (%8==0)
// ---------------------------------------------------------------------------
__global__ __launch_bounds__(256) void pv_kernel(
    const u16* __restrict__ SSb, const u16* __restrict__ vnat,
    u16* __restrict__ attoT, int b0)
{
    __shared__ u16 Vsb[128][36];   // [d][m]
    __shared__ u16 Psb[128][36];   // [n][m]
    const int t  = threadIdx.x;
    const int xx = blockIdx.x;
    const int panel = xx & 63;
    const int n0 = (xx >> 6) * 128;
    const int o  = panel & 7;
    const int lb = panel >> 3;
    const int gb = b0 + lb;
    const int w = t >> 6, l = t & 63;
    const int lrow = l & 31, lhalf = l >> 5;
    const int nsub = w & 1, dsub = w >> 1;

    f32x16 acc[2][2];
    acc[0][0] = zero16(); acc[0][1] = zero16();
    acc[1][0] = zero16(); acc[1][1] = zero16();

    for (int mc = 0; mc < 800; mc += 32) {
        #pragma unroll
        for (int cc = 0; cc < 2; cc++) {
            int ch  = t + 256 * cc;
            int row = ch >> 2;
            int c8  = (ch & 3) * 8;
            bool mok = (mc + c8 < Nc);
            u16x8 vv, pp;
            if (mok)
                vv = *reinterpret_cast<const u16x8*>(
                    &vnat[((size_t)gb * DHc + o * Dc + row) * Nc + mc + c8]);
            else
                #pragma unroll
                for (int q = 0; q < 8; q++) vv[q] = 0;
            if (mok && (n0 + row < Nc))
                pp = *reinterpret_cast<const u16x8*>(
                    &SSb[(((size_t)lb * Nc + n0 + row) * NHc + o) * Nc + mc + c8]);
            else
                #pragma unroll
                for (int q = 0; q < 8; q++) pp[q] = 0;
            *reinterpret_cast<u16x4*>(&Vsb[row][c8])     = (u16x4){vv[0],vv[1],vv[2],vv[3]};
            *reinterpret_cast<u16x4*>(&Vsb[row][c8 + 4]) = (u16x4){vv[4],vv[5],vv[6],vv[7]};
            *reinterpret_cast<u16x4*>(&Psb[row][c8])     = (u16x4){pp[0],pp[1],pp[2],pp[3]};
            *reinterpret_cast<u16x4*>(&Psb[row][c8 + 4]) = (u16x4){pp[4],pp[5],pp[6],pp[7]};
        }
        __syncthreads();
        #pragma unroll
        for (int k0 = 0; k0 < 32; k0 += 16) {
            s16x8 af[2], bf[2];
            #pragma unroll
            for (int di = 0; di < 2; di++)
                af[di] = ldfrag(&Psb[nsub * 64 + di * 32 + lrow][k0 + lhalf * 8]);
            #pragma unroll
            for (int ni = 0; ni < 2; ni++)
                bf[ni] = ldfrag(&Vsb[dsub * 64 + ni * 32 + lrow][k0 + lhalf * 8]);
            #pragma unroll
            for (int di = 0; di < 2; di++)
                #pragma unroll
                for (int ni = 0; ni < 2; ni++)
                    acc[di][ni] = mfma32(af[di], bf[ni], acc[di][ni]);
        }
        __syncthreads();
    }

    #pragma unroll
    for (int di = 0; di < 2; di++) {
        #pragma unroll
        for (int ni = 0; ni < 2; ni++) {
            int dcol = dsub * 64 + ni * 32 + lrow;
            #pragma unroll
            for (int reg = 0; reg < 16; reg++) {
                int nrow = n0 + nsub * 64 + di * 32 + (reg & 3) + 8 * (reg >> 2) + 4 * lhalf;
                if (nrow < Nc)
                    attoT[((size_t)gb * Nc + nrow) * DHc + o * Dc + dcol] =
                        f2bf(acc[di][ni][reg]);
            }
        }
    }
}

// ---------------------------------------------------------------------------
// pact[b][n][c] = bf16(relu(attoT[b][n][c] + vloc[b][c][n]^T)). 64x64 tiles.
// ---------------------------------------------------------------------------
__global__ __launch_bounds__(256) void prepP_kernel(
    const u16* __restrict__ attoT, const u16* __restrict__ vloc,
    u16* __restrict__ pact)
{
    __shared__ float tile[64][65];
    const int t = threadIdx.x;
    const int n0 = blockIdx.x * 64;
    const int c0 = blockIdx.y * 64;
    const int b  = blockIdx.z;
    const int jj = (t & 15) * 4, ii = t >> 4;
    #pragma unroll
    for (int rep = 0; rep < 4; rep++) {
        int c = c0 + ii + rep * 16;
        if (n0 + jj < Nc) {
            u16x4 v = *reinterpret_cast<const u16x4*>(
                &vloc[((size_t)b * DHc + c) * Nc + n0 + jj]);
            tile[ii + rep * 16][jj + 0] = bf2f(v[0]);
            tile[ii + rep * 16][jj + 1] = bf2f(v[1]);
            tile[ii + rep * 16][jj + 2] = bf2f(v[2]);
            tile[ii + rep * 16][jj + 3] = bf2f(v[3]);
        }
    }
    __syncthreads();
    const int cc = (t & 15) * 4;
    #pragma unroll
    for (int rep = 0; rep < 4; rep++) {
        int nn = (t >> 4) + rep * 16;
        int n  = n0 + nn;
        if (n < Nc) {
            size_t off = ((size_t)b * Nc + n) * DHc + c0 + cc;
            u16x4 a = *reinterpret_cast<const u16x4*>(&attoT[off]);
            u16x4 r;
            #pragma unroll
            for (int q = 0; q < 4; q++)
                r[q] = f2bf(fmaxf(bf2f(a[q]) + tile[cc + q][nn], 0.f));
            *reinterpret_cast<u16x4*>(&pact[off]) = r;
        }
    }
}

// ---------------------------------------------------------------------------
extern "C" void kernel_launch(void* const* d_in, const int* in_sizes, int n_in,
                              void* d_out, int out_size, void* d_ws, size_t ws_size,
                              hipStream_t stream)
{
    const float* x    = (const float*)d_in[0];
    const float* q_w  = (const float*)d_in[1];
    const float* q_b  = (const float*)d_in[2];
    const float* q_g  = (const float*)d_in[3];
    const float* q_be = (const float*)d_in[4];
    const float* q_m  = (const float*)d_in[5];
    const float* q_rv = (const float*)d_in[6];
    const float* k_w  = (const float*)d_in[7];
    const float* k_b  = (const float*)d_in[8];
    const float* k_g  = (const float*)d_in[9];
    const float* k_be = (const float*)d_in[10];
    const float* k_m  = (const float*)d_in[11];
    const float* k_rv = (const float*)d_in[12];
    const float* v_w  = (const float*)d_in[13];
    const float* v_b  = (const float*)d_in[14];
    const float* v_g  = (const float*)d_in[15];
    const float* v_be = (const float*)d_in[16];
    const float* v_m  = (const float*)d_in[17];
    const float* v_rv = (const float*)d_in[18];
    const float* vl_w = (const float*)d_in[19];
    const float* vl_b = (const float*)d_in[20];
    const float* vl_g = (const float*)d_in[21];
    const float* vl_be= (const float*)d_in[22];
    const float* vl_m = (const float*)d_in[23];
    const float* vl_rv= (const float*)d_in[24];
    const float* th1w = (const float*)d_in[25];
    const float* th1b = (const float*)d_in[26];
    const float* th2w = (const float*)d_in[27];
    const float* th2b = (const float*)d_in[28];
    const float* p_w  = (const float*)d_in[29];
    const float* p_b  = (const float*)d_in[30];
    const float* p_g  = (const float*)d_in[31];
    const float* p_be = (const float*)d_in[32];
    const float* p_m  = (const float*)d_in[33];
    const float* p_rv = (const float*)d_in[34];
    const float* btab = (const float*)d_in[35];
    const int*   bidx = (const int*)d_in[36];

    // ws ~170.6 MB (< 179.8 proven). Aliases:
    //  - xT: first 9.63 MB of attoT region (xT dead after projections).
    //  - pact aliases SSb (dead after last pv pass).
    char* wsb = (char*)d_ws;
    float* tab2T = (float*)wsb;                  wsb += (size_t)NHc * Nc * 4;
    u16*   qsb   = (u16*)wsb;                    wsb += (size_t)Bc * Nc * 256 * 2;
    u16*   Kt    = (u16*)wsb;                    wsb += (size_t)Bc * Nc * 256 * 2;
    u16*   vnat  = (u16*)wsb;                    wsb += (size_t)Bc * DHc * Nc * 2;
    u16*   vloc  = (u16*)wsb;                    wsb += (size_t)Bc * DHc * Nc * 2;
    u16*   SSb   = (u16*)wsb;                    wsb += (size_t)BPASS * Mrows * Nc * 2;
    u16*   qwb   = (u16*)wsb;                    wsb += (size_t)256 * DIMc * 2;
    u16*   kwb   = (u16*)wsb;                    wsb += (size_t)256 * DIMc * 2;
    u16*   vwb   = (u16*)wsb;                    wsb += (size_t)DHc * DIMc * 2;
    u16*   pwb   = (u16*)wsb;                    wsb += (size_t)DIMc * DHc * 2;
    float* qbb   = (float*)wsb;                  wsb += 256 * 4;
    float* kbb   = (float*)wsb;                  wsb += 256 * 4;
    float* vbb   = (float*)wsb;                  wsb += DHc * 4;
    float* pbb   = (float*)wsb;                  wsb += DIMc * 4;
    u16*   attoT = (u16*)wsb;                    wsb += (size_t)Bc * DHc * Nc * 2;
    u16*   xT    = attoT;   // alias: first 9.63 MB of attoT region
    u16*   pact  = SSb;     // alias: SSb dead after last pv pass

    // merged preamble: tab2 + castx + fold(q,k,v,p) in one dispatch
    prep_kernel<<<dim3(5113), 256, 0, stream>>>(
        btab, th1w, th1b, tab2T, x, xT,
        q_w, q_b, q_g, q_be, q_m, q_rv, qwb, qbb,
        k_w, k_b, k_g, k_be, k_m, k_rv, kwb, kbb,
        v_w, v_b, v_g, v_be, v_m, v_rv, vwb, vbb,
        p_w, p_b, p_g, p_be, p_m, p_rv, pwb, pbb);

    // q+k proj fused (z=0 -> q, z=1 -> k): 392 blocks in one dispatch
    mfma_gemm<DIMc, 128, false, false, true, false><<<dim3(2, 98, 2), 256, 0, stream>>>(
        xT, qwb, qbb, qsb, nullptr,
        (size_t)256 * DIMc, (size_t)Bc * Nc * 256, 256, 0, 256, 256);
    // v proj: XCD-pinned panels (x = ntile + 7*z, gridDim.x = 112)
    mfma_gemm<DIMc, 128, false, true, false, false><<<dim3(112, 8, 1), 256, 0, stream>>>(
        vwb, xT, vbb, vnat, nullptr,
        (size_t)Nc * DIMc, (size_t)DHc * Nc, 0, 7, Nc, Nc);

    dwconv_bn_kernel<<<dim3(Bc * DHc), 256, 0, stream>>>(
        vnat, vl_w, vl_b, vl_g, vl_be, vl_m, vl_rv, vloc);

    for (int b0 = 0; b0 < Bc; b0 += BPASS) {
        qk_kernel<<<dim3(7, 7, BPASS * NHc), 256, 0, stream>>>(
            qsb, Kt, SSb, b0);
        smth2_kernel<<<dim3(Nc, BPASS), 256, 0, stream>>>(
            SSb, th1w, tab2T, bidx, th2w, th2b);
        pv_kernel<<<dim3(7 * 8 * BPASS), 256, 0, stream>>>(SSb, vnat, attoT, b0);
    }

    prepP_kernel<<<dim3(13, 16, Bc), 256, 0, stream>>>(attoT, vloc, pact);
    // p proj: 64-col tiles -> 624 blocks, fp32 out
    mfma_gemm<DHc, 64, false, true, false, true><<<dim3(13, 3, Bc), 256, 0, stream>>>(
        pwb, pact, pbb, nullptr, (float*)d_out,
        (size_t)Nc * DHc, (size_t)DIMc * Nc, 0, 0, Nc, Nc);
}